// Round 7
// baseline (234.716 us; speedup 1.0000x reference)
//
#include <hip/hip_runtime.h>
#include <hip/hip_bf16.h>

typedef __attribute__((ext_vector_type(8))) short bf8_t;
typedef __attribute__((ext_vector_type(4))) float f32x4;

#define W_IMG 512
#define H_IMG 512
#define PLANES 96                  // 32 * 3
#define NPIX 25165824.0            // 96 * 512 * 512

#define BR 32                      // out rows per block
#define BC 64                      // out cols per block
#define PR 42                      // staged product rows  (BR + 10)
#define PC 84                      // staged product cols  (BC + 10, padded to 84)
#define HR 44                      // hout row dim (42 + 2 zero pad)
#define HC 65                      // hout cols (64 + 1 zero pad col)
#define MAPP (PR*PC)               // 3528 shorts per product map
#define MAPH (HC*HR)               // 2860 shorts per hout map
#define PRODSZ (5*MAPP)            // 17640
#define HOUTO  PRODSZ
#define HOUTSZ (5*MAPH)            // 14300

__global__ void ssim_zero(double* acc) {
    if (threadIdx.x == 0) acc[0] = 0.0;
}

__global__ void ssim_final(const double* __restrict__ acc, float* __restrict__ out) {
    if (threadIdx.x == 0) out[0] = (float)(1.0 - acc[0] / NPIX);
}

__device__ __forceinline__ unsigned pack_bf16(float lo, float hi) {
    union { __hip_bfloat16 h; unsigned short u; } A, B;
    A.h = __hip_bfloat16(lo);
    B.h = __hip_bfloat16(hi);
    return (unsigned)A.u | ((unsigned)B.u << 16);
}

__global__ __launch_bounds__(256)
void ssim_main(const float* __restrict__ img1,
               const float* __restrict__ img2,
               double* __restrict__ acc)
{
    // normalized 11-tap Gaussian, sigma=1.5 (matches reference _create_window)
    constexpr float G[11] = {
        0.00102838f, 0.00759875f, 0.03600077f, 0.10936070f, 0.21300540f,
        0.26601180f,
        0.21300540f, 0.10936070f, 0.03600077f, 0.00759875f, 0.00102838f };
    constexpr float K_C1 = 0.0001f;
    constexpr float K_C2 = 0.0009f;

    // 63,880 B: prod maps [5][42][84] bf16 then hout [5][65][44] bf16 (transposed)
    __shared__ short lds[PRODSZ + HOUTSZ];
    __shared__ float wred[4];

    const int tid = threadIdx.x;
    const int tx = blockIdx.x & 7;          // 8 col-tiles of 64
    const int ty = blockIdx.x >> 3;         // 16 row-tiles of 32
    const int c0 = tx * BC;
    const int r0 = ty * BR;
    const size_t pofs = (size_t)blockIdx.y * (H_IMG * W_IMG);
    const float* __restrict__ p1 = img1 + pofs;
    const float* __restrict__ p2 = img2 + pofs;

    // ---- stage 1: global fp32 -> 5 product maps, bf16 in LDS ----
    // LDS col sc ∈ [0,84) ↔ image col c0-5+sc ; LDS row r ↔ image row r0-5+r
    for (int t = tid; t < PR * (PC / 2); t += 256) {      // 1764 pair-tasks
        const int r = t / (PC / 2);
        const int p = t - r * (PC / 2);
        const int gr = r0 - 5 + r;
        const int gc = c0 - 5 + 2 * p;
        float a0 = 0.f, a1 = 0.f, b0 = 0.f, b1 = 0.f;
        if ((unsigned)gr < (unsigned)H_IMG) {
            const float* q1 = p1 + gr * W_IMG;
            const float* q2 = p2 + gr * W_IMG;
            if (gc >= 0 && gc < W_IMG - 1) {
                float2 va, vb;
                __builtin_memcpy(&va, q1 + gc, 8);
                __builtin_memcpy(&vb, q2 + gc, 8);
                a0 = va.x; a1 = va.y; b0 = vb.x; b1 = vb.y;
            } else {
                if ((unsigned)gc       < (unsigned)W_IMG) { a0 = q1[gc];     b0 = q2[gc];     }
                if ((unsigned)(gc + 1) < (unsigned)W_IMG) { a1 = q1[gc + 1]; b1 = q2[gc + 1]; }
            }
        }
        const int o = r * PC + 2 * p;
        *(unsigned*)&lds[0 * MAPP + o] = pack_bf16(a0, a1);
        *(unsigned*)&lds[1 * MAPP + o] = pack_bf16(b0, b1);
        *(unsigned*)&lds[2 * MAPP + o] = pack_bf16(a0 * a0, a1 * a1);
        *(unsigned*)&lds[3 * MAPP + o] = pack_bf16(b0 * b0, b1 * b1);
        *(unsigned*)&lds[4 * MAPP + o] = pack_bf16(a0 * b0, a1 * b1);
    }
    // zero hout pads (rows 42-43 every col; whole pad col 64) -> finite, and ×G=0
    for (int t = tid; t < 5 * 64 + 5 * (HR / 2); t += 256) {    // 430 tasks
        if (t < 5 * 64) {
            const int m = t >> 6, cc = t & 63;
            *(unsigned*)&lds[HOUTO + m * MAPH + cc * HR + 42] = 0u;
        } else {
            const int u = t - 5 * 64;
            const int m = u / (HR / 2), rr = u - m * (HR / 2);
            *(unsigned*)&lds[HOUTO + m * MAPH + 64 * HR + 2 * rr] = 0u;
        }
    }
    __syncthreads();

    // ---- Toeplitz G fragment: value(lane,j) = G[kb+j - n4] (0 outside band) ----
    // Serves as B for H-conv (B[k][n]=G[k-n]) and A for V-conv (A[m][k]=G[k-m]).
    // K-slot mapping is permutation-invariant: same formula on both operands.
    const int ln = tid & 63;
    const int wv = tid >> 6;           // wave = col chunk (16 cols)
    const int n4 = ln & 15;
    const int q4 = ln >> 4;
    const int kb = q4 * 8;

    union UU { unsigned u[4]; bf8_t v; };
    UU GU;
    #pragma unroll
    for (int p = 0; p < 4; ++p) {
        float glo = 0.f, ghi = 0.f;
        #pragma unroll
        for (int tt = 0; tt < 11; ++tt) {
            glo = (kb + 2 * p     - n4 == tt) ? G[tt] : glo;
            ghi = (kb + 2 * p + 1 - n4 == tt) ? G[tt] : ghi;
        }
        GU.u[p] = pack_bf16(glo, ghi);
    }
    const bf8_t gf = GU.v;
    const f32x4 zz = {0.f, 0.f, 0.f, 0.f};

    // ---- H stage: out[r][j] = Σ_t G[t]·P[r][j+t]; D[m][n], m=prod row, n=out col ----
    // wave wv covers out cols 16wv..16wv+15 (A patch LDS cols [16wv,16wv+32))
    #pragma unroll
    for (int rbi = 0; rbi < 3; ++rbi) {
        const int rb = (rbi == 2) ? 32 : rbi * 16;     // row chunks {0,16,32}
        #pragma unroll
        for (int mp = 0; mp < 5; ++mp) {
            const int abase = mp * MAPP + (rb + n4) * PC + wv * 16 + kb;
            UU AU;
            const uint2 alo = *(const uint2*)&lds[abase];
            const uint2 ahi = *(const uint2*)&lds[abase + 4];
            AU.u[0] = alo.x; AU.u[1] = alo.y; AU.u[2] = ahi.x; AU.u[3] = ahi.y;
            const f32x4 d = __builtin_amdgcn_mfma_f32_16x16x32_bf16(AU.v, gf, zz, 0, 0, 0);
            // D row = rb + 4*q4 + reg, col = 16wv + n4 -> hout[map][col][row] (transposed)
            const int row = rb + 4 * q4;
            short* hp = &lds[HOUTO + mp * MAPH + (wv * 16 + n4) * HR + row];
            const unsigned u0 = pack_bf16(d[0], d[1]);
            const unsigned u1 = pack_bf16(d[2], d[3]);
            if (rbi < 2) {
                *(uint2*)hp = make_uint2(u0, u1);
            } else {                      // rows 32..41 kept; 42+ discarded
                if (q4 < 2)        *(uint2*)hp = make_uint2(u0, u1);
                else if (q4 == 2)  *(unsigned*)hp = u0;     // rows 40,41
            }
        }
    }
    __syncthreads();

    // ---- V stage: out[i][c] = Σ_t G[t]·S[i+t][c] = Σ_k G[k-m]·S[rb+k][c] ----
    float lsum = 0.f;
    #pragma unroll
    for (int rbi = 0; rbi < 2; ++rbi) {
        const int rb2 = rbi * 16;
        f32x4 dm[5];
        #pragma unroll
        for (int mp = 0; mp < 5; ++mp) {
            const int bbase = HOUTO + mp * MAPH + (wv * 16 + n4) * HR + rb2 + kb;
            UU BU;
            const uint2 blo = *(const uint2*)&lds[bbase];
            const uint2 bhi = *(const uint2*)&lds[bbase + 4];
            BU.u[0] = blo.x; BU.u[1] = blo.y; BU.u[2] = bhi.x; BU.u[3] = bhi.y;
            dm[mp] = __builtin_amdgcn_mfma_f32_16x16x32_bf16(gf, BU.v, zz, 0, 0, 0);
        }
        #pragma unroll
        for (int r = 0; r < 4; ++r) {
            const float M1 = dm[0][r], M2 = dm[1][r];
            const float E11 = dm[2][r], E22 = dm[3][r], e12v = dm[4][r];
            const float mu1s = M1 * M1, mu2s = M2 * M2, mu12 = M1 * M2;
            const float v11 = fmaxf(E11 - mu1s, 0.f);
            const float v22 = fmaxf(E22 - mu2s, 0.f);
            const float v12 = e12v - mu12;
            const float num = fmaf(2.f, mu12, K_C1) * fmaf(2.f, v12, K_C2);
            const float den = (mu1s + mu2s + K_C1) * (v11 + v22 + K_C2);
            lsum = fmaf(num, __builtin_amdgcn_rcpf(den), lsum);
        }
    }

    // ---- wave reduce -> one atomic per block ----
    #pragma unroll
    for (int off = 32; off > 0; off >>= 1)
        lsum += __shfl_down(lsum, off, 64);
    if (ln == 0) wred[wv] = lsum;
    __syncthreads();
    if (tid == 0)
        atomicAdd(acc, (double)(wred[0] + wred[1] + wred[2] + wred[3]));
}

extern "C" void kernel_launch(void* const* d_in, const int* in_sizes, int n_in,
                              void* d_out, int out_size, void* d_ws, size_t ws_size,
                              hipStream_t stream) {
    const float* img1 = (const float*)d_in[0];
    const float* img2 = (const float*)d_in[1];
    float* out  = (float*)d_out;
    double* acc = (double*)d_ws;

    ssim_zero<<<dim3(1), dim3(64), 0, stream>>>(acc);
    ssim_main<<<dim3((W_IMG / BC) * (H_IMG / BR), PLANES), dim3(256), 0, stream>>>(img1, img2, acc);
    ssim_final<<<dim3(1), dim3(64), 0, stream>>>(acc, out);
}